// Round 9
// baseline (406.970 us; speedup 1.0000x reference)
//
#include <hip/hip_runtime.h>
#include <hip/hip_bf16.h>

// Problem constants (fixed by the reference)
#define VOCAB 50000
#define D     300
#define B_    64
#define LC    32
#define T_    256
#define LT    64
#define NSEL  5

// A-image geometry: 32 rows x 40 slots (16B = 8 f16), k padded 300->320,
// slot s stored at s ^ (m&7) -> conflict-free ds_read_b128.
// hi: uint4[0..1280), lo: uint4[1280..2560). 40960 B per batch.
#define A_U4   2560
#define A_HALF 20480
// B table row: 960 B = f16 hi [0,640) | u8 e5m2-trunc lo [640,960). 48 MB total.
#define TROWB  960

typedef _Float16 half8_t __attribute__((ext_vector_type(8)));
typedef _Float16 half4_t __attribute__((ext_vector_type(4)));
typedef float    f32x4   __attribute__((ext_vector_type(4)));

// e5m2-style lo encode: high byte of f16 bits, rounded (lo is tiny -> no overflow)
__device__ __forceinline__ unsigned char enc_lo(float x, _Float16 h) {
    _Float16 l = (_Float16)(x - (float)h);
    unsigned short b = __builtin_bit_cast(unsigned short, l);
    return (unsigned char)((unsigned short)(b + 0x80) >> 8);
}

// decode 8 lo-bytes -> half8 (f16 = byte << 8)
__device__ __forceinline__ half8_t decode_lo8(uint2 w) {
    unsigned int a = w.x, b = w.y;
    unsigned int p0 = ((a & 0xFFu) << 8) | ((a & 0xFF00u) << 16);
    unsigned int p1 = ((a & 0xFF0000u) >> 8) | (a & 0xFF000000u);
    unsigned int p2 = ((b & 0xFFu) << 8) | ((b & 0xFF00u) << 16);
    unsigned int p3 = ((b & 0xFF0000u) >> 8) | (b & 0xFF000000u);
    uint4 r = make_uint4(p0, p1, p2, p3);
    return __builtin_bit_cast(half8_t, r);
}

// ---------------- K0: whole-table f16hi + u8lo conversion --------------------
__global__ __launch_bounds__(256) void k_prep_table(const float* __restrict__ emb,
                                                    unsigned char* __restrict__ tab) {
    int r = blockIdx.x * 4 + (threadIdx.x >> 6);     // 12500*4 = 50000 rows
    int lane = threadIdx.x & 63;
    const float* src = emb + (size_t)r * D;
    unsigned char* row = tab + (size_t)r * TROWB;
#pragma unroll
    for (int i = 0; i < 2; ++i) {
        int k4 = lane + i * 64;                      // float4 index, need < 80
        if (k4 >= 80) continue;
        float4 v = (k4 < 75) ? *(const float4*)(src + 4 * k4)
                             : make_float4(0.f, 0.f, 0.f, 0.f);
        _Float16 h0 = (_Float16)v.x, h1 = (_Float16)v.y;
        _Float16 h2 = (_Float16)v.z, h3 = (_Float16)v.w;
        half4_t hv; hv[0] = h0; hv[1] = h1; hv[2] = h2; hv[3] = h3;
        *(half4_t*)(row + 8 * k4) = hv;
        unsigned int lw = (unsigned int)enc_lo(v.x, h0)
                        | ((unsigned int)enc_lo(v.y, h1) << 8)
                        | ((unsigned int)enc_lo(v.z, h2) << 16)
                        | ((unsigned int)enc_lo(v.w, h3) << 24);
        *(unsigned int*)(row + 640 + 4 * k4) = lw;
    }
}

// ---------------- K1: claim -> f16 hi/lo swizzled image in ws ----------------
__global__ void k_prep_claim(const int* __restrict__ claim,
                             const float* __restrict__ emb,
                             _Float16* __restrict__ wsA) {
    int row = blockIdx.x;                 // 0..B_*LC-1
    int b = row >> 5, m = row & 31;
    int tok = claim[row];
    const float* src = emb + (size_t)tok * D;
    _Float16* base = wsA + (size_t)b * A_HALF;
    for (int k = threadIdx.x; k < 320; k += 64) {
        float x = (k < D) ? src[k] : 0.0f;
        _Float16 h = (_Float16)x;
        float r = x - (float)h;
        _Float16 l = (_Float16)r;
        int sp = ((k >> 3) ^ (m & 7));
        int idx = (m * 40 + sp) * 8 + (k & 7);
        base[idx] = h;
        base[10240 + idx] = l;
    }
}

// hi/lo split of a float4 pair into half8 hi and half8 lo (slow path only)
__device__ __forceinline__ void split8(const float4& a, const float4& b,
                                       half8_t& hv, half8_t& lv) {
    float x[8] = {a.x, a.y, a.z, a.w, b.x, b.y, b.z, b.w};
#pragma unroll
    for (int i = 0; i < 8; ++i) {
        _Float16 h = (_Float16)x[i];
        hv[i] = h;
        lv[i] = (_Float16)(x[i] - (float)h);
    }
}

// ---------------- shared K-loop: U tile via f16x2-split MFMA ------------------
// Wave owns one t. acc[mi][ni] = 16x16 tile (c = mi*16+quad*4+reg, l = ni*16+ln).
template<bool FAST>
__device__ __forceinline__ void compute_U(const uint4* sA,
                                          const float* __restrict__ emb,
                                          const unsigned char* __restrict__ tab,
                                          const int* __restrict__ trow,
                                          int lane, f32x4 acc[2][4]) {
    int ln = lane & 15, quad = lane >> 4;
#pragma unroll
    for (int mi = 0; mi < 2; ++mi)
#pragma unroll
        for (int ni = 0; ni < 4; ++ni) acc[mi][ni] = (f32x4)0.0f;

    int arow0 = ln * 40;            // m = ln      (mi=0)
    int arow1 = (16 + ln) * 40;     // m = 16+ln   (mi=1)
    int key = ln & 7;

    if (FAST) {
        const unsigned char* rp[4];
#pragma unroll
        for (int ni = 0; ni < 4; ++ni) {
            int tok = trow[ni * 16 + ln];
            rp[ni] = tab + (size_t)tok * TROWB;
        }
        int qo = quad * 8;                 // frag k-offset within 32-k block
        // depth-2 pipeline: hi half8 + lo u8x8 double-buffered, base+imm loads
        half8_t bh[2][4]; uint2 bl8[2][4];
#pragma unroll
        for (int ni = 0; ni < 4; ++ni) {
            bh[0][ni]  = *(const half8_t*)(rp[ni] + 2 * qo);
            bl8[0][ni] = *(const uint2*)(rp[ni] + 640 + qo);
        }
#pragma unroll
        for (int ks = 0; ks < 10; ++ks) {
            int cur = ks & 1, nxt = cur ^ 1;
            if (ks < 9) {
                int ko = (ks + 1) * 32 + qo;
#pragma unroll
                for (int ni = 0; ni < 4; ++ni) {
                    bh[nxt][ni]  = *(const half8_t*)(rp[ni] + 2 * ko);
                    bl8[nxt][ni] = *(const uint2*)(rp[ni] + 640 + ko);
                }
            }
            int sp = (ks * 4 + quad) ^ key;
            half8_t ah[2], al[2];
            ah[0] = __builtin_bit_cast(half8_t, sA[arow0 + sp]);
            al[0] = __builtin_bit_cast(half8_t, sA[1280 + arow0 + sp]);
            ah[1] = __builtin_bit_cast(half8_t, sA[arow1 + sp]);
            al[1] = __builtin_bit_cast(half8_t, sA[1280 + arow1 + sp]);
            half8_t bl[4];
#pragma unroll
            for (int ni = 0; ni < 4; ++ni) bl[ni] = decode_lo8(bl8[cur][ni]);
#pragma unroll
            for (int mi = 0; mi < 2; ++mi)
#pragma unroll
                for (int ni = 0; ni < 4; ++ni) {
                    acc[mi][ni] = __builtin_amdgcn_mfma_f32_16x16x32_f16(ah[mi], bh[cur][ni], acc[mi][ni], 0, 0, 0);
                    acc[mi][ni] = __builtin_amdgcn_mfma_f32_16x16x32_f16(ah[mi], bl[ni], acc[mi][ni], 0, 0, 0);
                    acc[mi][ni] = __builtin_amdgcn_mfma_f32_16x16x32_f16(al[mi], bh[cur][ni], acc[mi][ni], 0, 0, 0);
                }
        }
    } else {
        const float* bp[4];
#pragma unroll
        for (int ni = 0; ni < 4; ++ni) {
            int tok = trow[ni * 16 + ln];
            bp[ni] = emb + (size_t)tok * D;
        }
#pragma unroll 1
        for (int ks = 0; ks < 10; ++ks) {
            int kb = ks * 32 + quad * 8;
            int ka = kb > 296 ? 296 : kb;
            int kb4 = kb + 4;
            int kbb = kb4 > 296 ? 296 : kb4;
            float4 b0[4], b1[4];
#pragma unroll
            for (int ni = 0; ni < 4; ++ni) {
                b0[ni] = *(const float4*)(bp[ni] + ka);
                b1[ni] = *(const float4*)(bp[ni] + kbb);
            }
            if (kb >= 296) {
                float4 z = make_float4(0.f, 0.f, 0.f, 0.f);
#pragma unroll
                for (int ni = 0; ni < 4; ++ni) {
                    if (kb >= 300) b0[ni] = z;
                    b1[ni] = z;
                }
            }
            int sp = (ks * 4 + quad) ^ key;
            half8_t ah[2], al[2];
            ah[0] = __builtin_bit_cast(half8_t, sA[arow0 + sp]);
            al[0] = __builtin_bit_cast(half8_t, sA[1280 + arow0 + sp]);
            ah[1] = __builtin_bit_cast(half8_t, sA[arow1 + sp]);
            al[1] = __builtin_bit_cast(half8_t, sA[1280 + arow1 + sp]);
            half8_t bh[4], bl[4];
#pragma unroll
            for (int ni = 0; ni < 4; ++ni) split8(b0[ni], b1[ni], bh[ni], bl[ni]);
#pragma unroll
            for (int mi = 0; mi < 2; ++mi)
#pragma unroll
                for (int ni = 0; ni < 4; ++ni) {
                    acc[mi][ni] = __builtin_amdgcn_mfma_f32_16x16x32_f16(ah[mi], bh[ni], acc[mi][ni], 0, 0, 0);
                    acc[mi][ni] = __builtin_amdgcn_mfma_f32_16x16x32_f16(ah[mi], bl[ni], acc[mi][ni], 0, 0, 0);
                    acc[mi][ni] = __builtin_amdgcn_mfma_f32_16x16x32_f16(al[mi], bh[ni], acc[mi][ni], 0, 0, 0);
                }
        }
    }
}

__device__ __forceinline__ float xmax4(float v) {
    v = fmaxf(v, __shfl_xor(v, 1)); v = fmaxf(v, __shfl_xor(v, 2));
    v = fmaxf(v, __shfl_xor(v, 4)); v = fmaxf(v, __shfl_xor(v, 8));
    return v;
}
__device__ __forceinline__ float xsum4(float v) {
    v += __shfl_xor(v, 1); v += __shfl_xor(v, 2);
    v += __shfl_xor(v, 4); v += __shfl_xor(v, 8);
    return v;
}

// ---------------- K2: target scores (wave-per-t, barrier-free K-loop) --------
template<bool FAST>
__global__ __launch_bounds__(256, 4) void k_scores(const int* __restrict__ targets,
                                                   const float* __restrict__ emb,
                                                   const unsigned char* __restrict__ tab,
                                                   const _Float16* __restrict__ wsA,
                                                   float* __restrict__ wsScr) {
    __shared__ __align__(16) uint4 sA[A_U4];   // 40960 B -> 4 blocks/CU (LDS cap)
    int b = blockIdx.y, tid = threadIdx.x;
    {
        const uint4* src = (const uint4*)(wsA + (size_t)b * A_HALF);
        for (int i = tid; i < A_U4; i += 256) sA[i] = src[i];
    }
    __syncthreads();

    int lane = tid & 63, wave = tid >> 6;
    int t = blockIdx.x * 4 + wave;
    const int* trow = targets + ((size_t)b * T_ + t) * LT;

    f32x4 acc[2][4];
    compute_U<FAST>(sA, emb, tab, trow, lane, acc);

    // softmax over l per c, max over c, sum over l — all in-wave
    float score_l[4] = {0.f, 0.f, 0.f, 0.f};
#pragma unroll
    for (int mi = 0; mi < 2; ++mi)
#pragma unroll
        for (int r = 0; r < 4; ++r) {
            float m = fmaxf(fmaxf(acc[mi][0][r], acc[mi][1][r]),
                            fmaxf(acc[mi][2][r], acc[mi][3][r]));
            m = xmax4(m);                     // max over 64 l for this c
            float p[4], s = 0.f;
#pragma unroll
            for (int ni = 0; ni < 4; ++ni) { p[ni] = __expf(acc[mi][ni][r] - m); s += p[ni]; }
            s = xsum4(s);                     // denom over 64 l
            float rv = 1.0f / s;
#pragma unroll
            for (int ni = 0; ni < 4; ++ni) score_l[ni] = fmaxf(score_l[ni], p[ni] * rv);
        }
    float tot = 0.f;
#pragma unroll
    for (int ni = 0; ni < 4; ++ni) {
        float v = score_l[ni];                // fold max over c across quads
        v = fmaxf(v, __shfl_xor(v, 16));
        v = fmaxf(v, __shfl_xor(v, 32));
        tot += v;
    }
    tot = xsum4(tot);                         // sum over the 16 ln-columns
    if (lane == 0) wsScr[b * T_ + t] = tot;
}

// ---------------- K3: top-5 per batch (descending, lowest-index ties) --------
__global__ void k_topn(const float* __restrict__ wsScr, int* __restrict__ wsIdx) {
    int b = blockIdx.x;
    int tid = threadIdx.x;              // 64 threads = 1 wave
    float v[4];
    for (int i = 0; i < 4; ++i) v[i] = wsScr[b * T_ + tid + 64 * i];
    for (int r = 0; r < NSEL; ++r) {
        float bv = v[0]; int bi = tid;
        for (int i = 1; i < 4; ++i) {
            int idx = tid + 64 * i;
            if (v[i] > bv) { bv = v[i]; bi = idx; }
        }
        for (int off = 32; off > 0; off >>= 1) {
            float ov = __shfl_down(bv, off);
            int   oi = __shfl_down(bi, off);
            if (ov > bv || (ov == bv && oi < bi)) { bv = ov; bi = oi; }
        }
        bi = __shfl(bi, 0);
        if (tid == 0) wsIdx[b * NSEL + r] = bi;
        if ((bi & 63) == tid) v[bi >> 6] = -1e30f;   // remove winner
    }
}

// ---------------- K4: recompute selected tiles, L2-normalize rows ------------
// One 64-thread block (1 wave) per (b, j) -> 320 parallel blocks.
template<bool FAST>
__global__ __launch_bounds__(64) void k_output(const int* __restrict__ targets,
                                               const float* __restrict__ emb,
                                               const unsigned char* __restrict__ tab,
                                               const _Float16* __restrict__ wsA,
                                               const int* __restrict__ wsIdx,
                                               float* __restrict__ out) {
    __shared__ __align__(16) uint4 sA[A_U4];
    int b = blockIdx.y, j = blockIdx.x;
    int lane = threadIdx.x;             // 1 wave = 1 tile
    {
        const uint4* src = (const uint4*)(wsA + (size_t)b * A_HALF);
        for (int i = lane; i < A_U4; i += 64) sA[i] = src[i];
    }
    __syncthreads();

    int t = wsIdx[b * NSEL + j];
    const int* trow = targets + ((size_t)b * T_ + t) * LT;
    f32x4 acc[2][4];
    compute_U<FAST>(sA, emb, tab, trow, lane, acc);

    int ln = lane & 15, quad = lane >> 4;
    float* obase = out + (size_t)(b * NSEL + j) * (LC * LT);
#pragma unroll
    for (int mi = 0; mi < 2; ++mi)
#pragma unroll
        for (int r = 0; r < 4; ++r) {
            float ss = 0.f;
#pragma unroll
            for (int ni = 0; ni < 4; ++ni) ss = fmaf(acc[mi][ni][r], acc[mi][ni][r], ss);
            ss = xsum4(ss);                          // sum over 64 l
            float rinv = 1.0f / sqrtf(ss);
            int c = mi * 16 + quad * 4 + r;
#pragma unroll
            for (int ni = 0; ni < 4; ++ni)
                obase[c * LT + ni * 16 + ln] = acc[mi][ni][r] * rinv;
        }
}

extern "C" void kernel_launch(void* const* d_in, const int* in_sizes, int n_in,
                              void* d_out, int out_size, void* d_ws, size_t ws_size,
                              hipStream_t stream) {
    const int*   claim   = (const int*)d_in[0];
    const int*   targets = (const int*)d_in[1];
    const float* emb     = (const float*)d_in[2];
    // d_in[3] is n (=5), compile-time NSEL

    const size_t tabBytes = (size_t)VOCAB * TROWB;                     // 48 MB
    const size_t restBytes = (size_t)B_ * A_HALF * sizeof(_Float16)
                           + (size_t)B_ * T_ * sizeof(float)
                           + (size_t)B_ * NSEL * sizeof(int) + 256;
    bool fast = ws_size >= tabBytes + restBytes;   // deterministic per run

    char* p = (char*)d_ws;
    unsigned char* tab = nullptr;
    if (fast) { tab = (unsigned char*)p; p += tabBytes; }
    _Float16* wsA = (_Float16*)p; p += (size_t)B_ * A_HALF * sizeof(_Float16);
    float* wsScr = (float*)p;     p += (size_t)B_ * T_ * sizeof(float);
    int*   wsIdx = (int*)p;
    float* out   = (float*)d_out;

    if (fast)
        k_prep_table<<<dim3(VOCAB / 4), dim3(256), 0, stream>>>(emb, tab);
    k_prep_claim<<<dim3(B_ * LC), dim3(64), 0, stream>>>(claim, emb, wsA);
    if (fast) {
        k_scores<true><<<dim3(T_ / 4, B_), dim3(256), 0, stream>>>(targets, emb, tab, wsA, wsScr);
        k_topn<<<dim3(B_), dim3(64), 0, stream>>>(wsScr, wsIdx);
        k_output<true><<<dim3(NSEL, B_), dim3(64), 0, stream>>>(targets, emb, tab, wsA, wsIdx, out);
    } else {
        k_scores<false><<<dim3(T_ / 4, B_), dim3(256), 0, stream>>>(targets, emb, tab, wsA, wsScr);
        k_topn<<<dim3(B_), dim3(64), 0, stream>>>(wsScr, wsIdx);
        k_output<false><<<dim3(NSEL, B_), dim3(64), 0, stream>>>(targets, emb, tab, wsA, wsIdx, out);
    }
}

// Round 10
// 340.852 us; speedup vs baseline: 1.1940x; 1.1940x over previous
//
#include <hip/hip_runtime.h>
#include <hip/hip_bf16.h>

// Problem constants (fixed by the reference)
#define VOCAB 50000
#define D     300
#define B_    64
#define LC    32
#define T_    256
#define LT    64
#define NSEL  5

// B table row: 1024 B, 128-line aligned:
//   [f16 hi x320 = 640 B][u8 e5m2-trunc lo x320 = 320 B][64 B zero pad]
#define TROWB  1024
// A image per batch (ws + LDS), 30976 B total:
//   hi: uint4[0..1280)  = 32 rows x 40 slots (16 B), slot s at s^(m&7) (swizzled)
//   lo: bytes [20480..30976) = 32 rows x 328 B (8 B per k-slot, 8 B pad/row;
//       328/4=82 words/row -> 82*ln mod 32 distinct across 16 lanes: conflict-free)
#define A_HI_U4    1280
#define A_LO_OFF   20480
#define A_LO_STRIDE 328
#define A_IMG_BYTES 30976
#define A_IMG_U4    1936

typedef _Float16 half8_t __attribute__((ext_vector_type(8)));
typedef _Float16 half4_t __attribute__((ext_vector_type(4)));
typedef float    f32x4   __attribute__((ext_vector_type(4)));

// e5m2-style lo encode: rounded high byte of f16 bits (lo tiny -> no overflow)
__device__ __forceinline__ unsigned char enc_lo(float x, _Float16 h) {
    _Float16 l = (_Float16)(x - (float)h);
    unsigned short b = __builtin_bit_cast(unsigned short, l);
    return (unsigned char)((unsigned short)(b + 0x80) >> 8);
}

// decode 8 lo-bytes -> half8 (f16 = byte << 8)
__device__ __forceinline__ half8_t decode_lo8(uint2 w) {
    unsigned int a = w.x, b = w.y;
    unsigned int p0 = ((a & 0xFFu) << 8) | ((a & 0xFF00u) << 16);
    unsigned int p1 = ((a & 0xFF0000u) >> 8) | (a & 0xFF000000u);
    unsigned int p2 = ((b & 0xFFu) << 8) | ((b & 0xFF00u) << 16);
    unsigned int p3 = ((b & 0xFF0000u) >> 8) | (b & 0xFF000000u);
    uint4 r = make_uint4(p0, p1, p2, p3);
    return __builtin_bit_cast(half8_t, r);
}

// ---------------- K0: whole-table f16hi + u8lo conversion (1024 B rows) ------
__global__ __launch_bounds__(256) void k_prep_table(const float* __restrict__ emb,
                                                    unsigned char* __restrict__ tab) {
    int r = blockIdx.x * 4 + (threadIdx.x >> 6);     // 12500*4 = 50000 rows
    int lane = threadIdx.x & 63;
    const float* src = emb + (size_t)r * D;
    unsigned char* row = tab + (size_t)r * TROWB;
#pragma unroll
    for (int i = 0; i < 2; ++i) {
        int k4 = lane + i * 64;                      // float4 index < 80
        if (k4 >= 80) continue;
        float4 v = (k4 < 75) ? *(const float4*)(src + 4 * k4)
                             : make_float4(0.f, 0.f, 0.f, 0.f);
        _Float16 h0 = (_Float16)v.x, h1 = (_Float16)v.y;
        _Float16 h2 = (_Float16)v.z, h3 = (_Float16)v.w;
        half4_t hv; hv[0] = h0; hv[1] = h1; hv[2] = h2; hv[3] = h3;
        *(half4_t*)(row + 8 * k4) = hv;
        unsigned int lw = (unsigned int)enc_lo(v.x, h0)
                        | ((unsigned int)enc_lo(v.y, h1) << 8)
                        | ((unsigned int)enc_lo(v.z, h2) << 16)
                        | ((unsigned int)enc_lo(v.w, h3) << 24);
        *(unsigned int*)(row + 640 + 4 * k4) = lw;
    }
    if (lane < 4)                                    // zero the 64 B pad
        *(uint4*)(row + 960 + 16 * lane) = make_uint4(0, 0, 0, 0);
}

// ---------------- K1: claim -> packed hi/lo swizzled image in ws -------------
__global__ void k_prep_claim(const int* __restrict__ claim,
                             const float* __restrict__ emb,
                             unsigned char* __restrict__ wsA) {
    int row = blockIdx.x;                 // 0..B_*LC-1
    int b = row >> 5, m = row & 31;
    int tok = claim[row];
    const float* src = emb + (size_t)tok * D;
    unsigned char* base = wsA + (size_t)b * A_IMG_BYTES;
    _Float16* hbase = (_Float16*)base;
    for (int k = threadIdx.x; k < 320; k += 64) {
        float x = (k < D) ? src[k] : 0.0f;
        _Float16 h = (_Float16)x;
        int sp = ((k >> 3) ^ (m & 7));
        hbase[(m * 40 + sp) * 8 + (k & 7)] = h;
        base[A_LO_OFF + m * A_LO_STRIDE + (k >> 3) * 8 + (k & 7)] = enc_lo(x, h);
    }
}

// hi/lo split of a float4 pair into half8 hi and half8 lo (slow path only)
__device__ __forceinline__ void split8(const float4& a, const float4& b,
                                       half8_t& hv, half8_t& lv) {
    float x[8] = {a.x, a.y, a.z, a.w, b.x, b.y, b.z, b.w};
#pragma unroll
    for (int i = 0; i < 8; ++i) {
        _Float16 h = (_Float16)x[i];
        hv[i] = h;
        lv[i] = (_Float16)(x[i] - (float)h);
    }
}

// ---------------- shared K-loop: U tile via f16x2-split MFMA ------------------
// Wave owns one t. acc[mi][ni] = 16x16 tile (c = mi*16+quad*4+reg, l = ni*16+ln).
template<bool FAST>
__device__ __forceinline__ void compute_U(const uint4* sA,
                                          const float* __restrict__ emb,
                                          const unsigned char* __restrict__ tab,
                                          const int* __restrict__ trow,
                                          int lane, f32x4 acc[2][4]) {
    int ln = lane & 15, quad = lane >> 4;
#pragma unroll
    for (int mi = 0; mi < 2; ++mi)
#pragma unroll
        for (int ni = 0; ni < 4; ++ni) acc[mi][ni] = (f32x4)0.0f;

    int arow0 = ln * 40;            // m = ln      (mi=0)
    int arow1 = (16 + ln) * 40;     // m = 16+ln   (mi=1)
    int key = ln & 7;
    const unsigned char* sAb = (const unsigned char*)sA;
    int lo0 = A_LO_OFF + ln * A_LO_STRIDE;
    int lo1 = A_LO_OFF + (16 + ln) * A_LO_STRIDE;
    int qo = quad * 8;

    if (FAST) {
        const unsigned char* rp[4];
#pragma unroll
        for (int ni = 0; ni < 4; ++ni) {
            int tok = trow[ni * 16 + ln];
            rp[ni] = tab + (size_t)tok * TROWB;
        }
        // depth-2 pipeline: hi half8 + lo u8x8 double-buffered, base+imm loads
        half8_t bh[2][4]; uint2 bl8[2][4];
#pragma unroll
        for (int ni = 0; ni < 4; ++ni) {
            bh[0][ni]  = *(const half8_t*)(rp[ni] + 2 * qo);
            bl8[0][ni] = *(const uint2*)(rp[ni] + 640 + qo);
        }
#pragma unroll
        for (int ks = 0; ks < 10; ++ks) {
            int cur = ks & 1, nxt = cur ^ 1;
            if (ks < 9) {
                int ko = (ks + 1) * 32 + qo;
#pragma unroll
                for (int ni = 0; ni < 4; ++ni) {
                    bh[nxt][ni]  = *(const half8_t*)(rp[ni] + 2 * ko);
                    bl8[nxt][ni] = *(const uint2*)(rp[ni] + 640 + ko);
                }
            }
            int sp = (ks * 4 + quad) ^ key;
            int lslot = (ks * 4 + quad) * 8;
            half8_t ah[2], al[2];
            ah[0] = __builtin_bit_cast(half8_t, sA[arow0 + sp]);
            ah[1] = __builtin_bit_cast(half8_t, sA[arow1 + sp]);
            al[0] = decode_lo8(*(const uint2*)(sAb + lo0 + lslot));
            al[1] = decode_lo8(*(const uint2*)(sAb + lo1 + lslot));
            half8_t bl[4];
#pragma unroll
            for (int ni = 0; ni < 4; ++ni) bl[ni] = decode_lo8(bl8[cur][ni]);
#pragma unroll
            for (int mi = 0; mi < 2; ++mi)
#pragma unroll
                for (int ni = 0; ni < 4; ++ni) {
                    acc[mi][ni] = __builtin_amdgcn_mfma_f32_16x16x32_f16(ah[mi], bh[cur][ni], acc[mi][ni], 0, 0, 0);
                    acc[mi][ni] = __builtin_amdgcn_mfma_f32_16x16x32_f16(ah[mi], bl[ni], acc[mi][ni], 0, 0, 0);
                    acc[mi][ni] = __builtin_amdgcn_mfma_f32_16x16x32_f16(al[mi], bh[cur][ni], acc[mi][ni], 0, 0, 0);
                }
        }
    } else {
        const float* bp[4];
#pragma unroll
        for (int ni = 0; ni < 4; ++ni) {
            int tok = trow[ni * 16 + ln];
            bp[ni] = emb + (size_t)tok * D;
        }
#pragma unroll 1
        for (int ks = 0; ks < 10; ++ks) {
            int kb = ks * 32 + qo;
            int ka = kb > 296 ? 296 : kb;
            int kb4 = kb + 4;
            int kbb = kb4 > 296 ? 296 : kb4;
            float4 b0[4], b1[4];
#pragma unroll
            for (int ni = 0; ni < 4; ++ni) {
                b0[ni] = *(const float4*)(bp[ni] + ka);
                b1[ni] = *(const float4*)(bp[ni] + kbb);
            }
            if (kb >= 296) {
                float4 z = make_float4(0.f, 0.f, 0.f, 0.f);
#pragma unroll
                for (int ni = 0; ni < 4; ++ni) {
                    if (kb >= 300) b0[ni] = z;
                    b1[ni] = z;
                }
            }
            int sp = (ks * 4 + quad) ^ key;
            int lslot = (ks * 4 + quad) * 8;
            half8_t ah[2], al[2];
            ah[0] = __builtin_bit_cast(half8_t, sA[arow0 + sp]);
            ah[1] = __builtin_bit_cast(half8_t, sA[arow1 + sp]);
            al[0] = decode_lo8(*(const uint2*)(sAb + lo0 + lslot));
            al[1] = decode_lo8(*(const uint2*)(sAb + lo1 + lslot));
            half8_t bh[4], bl[4];
#pragma unroll
            for (int ni = 0; ni < 4; ++ni) split8(b0[ni], b1[ni], bh[ni], bl[ni]);
#pragma unroll
            for (int mi = 0; mi < 2; ++mi)
#pragma unroll
                for (int ni = 0; ni < 4; ++ni) {
                    acc[mi][ni] = __builtin_amdgcn_mfma_f32_16x16x32_f16(ah[mi], bh[ni], acc[mi][ni], 0, 0, 0);
                    acc[mi][ni] = __builtin_amdgcn_mfma_f32_16x16x32_f16(ah[mi], bl[ni], acc[mi][ni], 0, 0, 0);
                    acc[mi][ni] = __builtin_amdgcn_mfma_f32_16x16x32_f16(al[mi], bh[ni], acc[mi][ni], 0, 0, 0);
                }
        }
    }
}

__device__ __forceinline__ float xmax4(float v) {
    v = fmaxf(v, __shfl_xor(v, 1)); v = fmaxf(v, __shfl_xor(v, 2));
    v = fmaxf(v, __shfl_xor(v, 4)); v = fmaxf(v, __shfl_xor(v, 8));
    return v;
}
__device__ __forceinline__ float xsum4(float v) {
    v += __shfl_xor(v, 1); v += __shfl_xor(v, 2);
    v += __shfl_xor(v, 4); v += __shfl_xor(v, 8);
    return v;
}

// ---------------- K2: target scores (wave-per-t, barrier-free K-loop) --------
template<bool FAST>
__global__ __launch_bounds__(256, 4) void k_scores(const int* __restrict__ targets,
                                                   const float* __restrict__ emb,
                                                   const unsigned char* __restrict__ tab,
                                                   const unsigned char* __restrict__ wsA,
                                                   float* __restrict__ wsScr) {
    __shared__ __align__(16) uint4 sA[A_IMG_U4];   // 30976 B -> 5 blocks/CU
    int b = blockIdx.y, tid = threadIdx.x;
    {
        const uint4* src = (const uint4*)(wsA + (size_t)b * A_IMG_BYTES);
        for (int i = tid; i < A_IMG_U4; i += 256) sA[i] = src[i];
    }
    __syncthreads();

    int lane = tid & 63, wave = tid >> 6;
    int t = blockIdx.x * 4 + wave;
    const int* trow = targets + ((size_t)b * T_ + t) * LT;

    f32x4 acc[2][4];
    compute_U<FAST>(sA, emb, tab, trow, lane, acc);

    // softmax over l per c, max over c, sum over l — all in-wave
    float score_l[4] = {0.f, 0.f, 0.f, 0.f};
#pragma unroll
    for (int mi = 0; mi < 2; ++mi)
#pragma unroll
        for (int r = 0; r < 4; ++r) {
            float m = fmaxf(fmaxf(acc[mi][0][r], acc[mi][1][r]),
                            fmaxf(acc[mi][2][r], acc[mi][3][r]));
            m = xmax4(m);                     // max over 64 l for this c
            float p[4], s = 0.f;
#pragma unroll
            for (int ni = 0; ni < 4; ++ni) { p[ni] = __expf(acc[mi][ni][r] - m); s += p[ni]; }
            s = xsum4(s);                     // denom over 64 l
            float rv = 1.0f / s;
#pragma unroll
            for (int ni = 0; ni < 4; ++ni) score_l[ni] = fmaxf(score_l[ni], p[ni] * rv);
        }
    float tot = 0.f;
#pragma unroll
    for (int ni = 0; ni < 4; ++ni) {
        float v = score_l[ni];                // fold max over c across quads
        v = fmaxf(v, __shfl_xor(v, 16));
        v = fmaxf(v, __shfl_xor(v, 32));
        tot += v;
    }
    tot = xsum4(tot);                         // sum over the 16 ln-columns
    if (lane == 0) wsScr[b * T_ + t] = tot;
}

// ---------------- K3: top-5 per batch (descending, lowest-index ties) --------
__global__ void k_topn(const float* __restrict__ wsScr, int* __restrict__ wsIdx) {
    int b = blockIdx.x;
    int tid = threadIdx.x;              // 64 threads = 1 wave
    float v[4];
    for (int i = 0; i < 4; ++i) v[i] = wsScr[b * T_ + tid + 64 * i];
    for (int r = 0; r < NSEL; ++r) {
        float bv = v[0]; int bi = tid;
        for (int i = 1; i < 4; ++i) {
            int idx = tid + 64 * i;
            if (v[i] > bv) { bv = v[i]; bi = idx; }
        }
        for (int off = 32; off > 0; off >>= 1) {
            float ov = __shfl_down(bv, off);
            int   oi = __shfl_down(bi, off);
            if (ov > bv || (ov == bv && oi < bi)) { bv = ov; bi = oi; }
        }
        bi = __shfl(bi, 0);
        if (tid == 0) wsIdx[b * NSEL + r] = bi;
        if ((bi & 63) == tid) v[bi >> 6] = -1e30f;   // remove winner
    }
}

// ---------------- K4: recompute selected tiles, L2-normalize rows ------------
// One 64-thread block (1 wave) per (b, j) -> 320 parallel blocks.
template<bool FAST>
__global__ __launch_bounds__(64) void k_output(const int* __restrict__ targets,
                                               const float* __restrict__ emb,
                                               const unsigned char* __restrict__ tab,
                                               const unsigned char* __restrict__ wsA,
                                               const int* __restrict__ wsIdx,
                                               float* __restrict__ out) {
    __shared__ __align__(16) uint4 sA[A_IMG_U4];
    int b = blockIdx.y, j = blockIdx.x;
    int lane = threadIdx.x;             // 1 wave = 1 tile
    {
        const uint4* src = (const uint4*)(wsA + (size_t)b * A_IMG_BYTES);
        for (int i = lane; i < A_IMG_U4; i += 64) sA[i] = src[i];
    }
    __syncthreads();

    int t = wsIdx[b * NSEL + j];
    const int* trow = targets + ((size_t)b * T_ + t) * LT;
    f32x4 acc[2][4];
    compute_U<FAST>(sA, emb, tab, trow, lane, acc);

    int ln = lane & 15, quad = lane >> 4;
    float* obase = out + (size_t)(b * NSEL + j) * (LC * LT);
#pragma unroll
    for (int mi = 0; mi < 2; ++mi)
#pragma unroll
        for (int r = 0; r < 4; ++r) {
            float ss = 0.f;
#pragma unroll
            for (int ni = 0; ni < 4; ++ni) ss = fmaf(acc[mi][ni][r], acc[mi][ni][r], ss);
            ss = xsum4(ss);                          // sum over 64 l
            float rinv = 1.0f / sqrtf(ss);
            int c = mi * 16 + quad * 4 + r;
#pragma unroll
            for (int ni = 0; ni < 4; ++ni)
                obase[c * LT + ni * 16 + ln] = acc[mi][ni][r] * rinv;
        }
}

extern "C" void kernel_launch(void* const* d_in, const int* in_sizes, int n_in,
                              void* d_out, int out_size, void* d_ws, size_t ws_size,
                              hipStream_t stream) {
    const int*   claim   = (const int*)d_in[0];
    const int*   targets = (const int*)d_in[1];
    const float* emb     = (const float*)d_in[2];
    // d_in[3] is n (=5), compile-time NSEL

    const size_t tabBytes = (size_t)VOCAB * TROWB;                     // 51.2 MB
    const size_t restBytes = (size_t)B_ * A_IMG_BYTES
                           + (size_t)B_ * T_ * sizeof(float)
                           + (size_t)B_ * NSEL * sizeof(int) + 256;
    bool fast = ws_size >= tabBytes + restBytes;   // deterministic per run

    char* p = (char*)d_ws;
    unsigned char* tab = nullptr;
    if (fast) { tab = (unsigned char*)p; p += tabBytes; }
    unsigned char* wsA = (unsigned char*)p; p += (size_t)B_ * A_IMG_BYTES;
    float* wsScr = (float*)p;               p += (size_t)B_ * T_ * sizeof(float);
    int*   wsIdx = (int*)p;
    float* out   = (float*)d_out;

    if (fast)
        k_prep_table<<<dim3(VOCAB / 4), dim3(256), 0, stream>>>(emb, tab);
    k_prep_claim<<<dim3(B_ * LC), dim3(64), 0, stream>>>(claim, emb, wsA);
    if (fast) {
        k_scores<true><<<dim3(T_ / 4, B_), dim3(256), 0, stream>>>(targets, emb, tab, wsA, wsScr);
        k_topn<<<dim3(B_), dim3(64), 0, stream>>>(wsScr, wsIdx);
        k_output<true><<<dim3(NSEL, B_), dim3(64), 0, stream>>>(targets, emb, tab, wsA, wsIdx, out);
    } else {
        k_scores<false><<<dim3(T_ / 4, B_), dim3(256), 0, stream>>>(targets, emb, tab, wsA, wsScr);
        k_topn<<<dim3(B_), dim3(64), 0, stream>>>(wsScr, wsIdx);
        k_output<false><<<dim3(NSEL, B_), dim3(64), 0, stream>>>(targets, emb, tab, wsA, wsIdx, out);
    }
}